// Round 11
// baseline (117.296 us; speedup 1.0000x reference)
//
#include <hip/hip_runtime.h>

// Problem constants
#define NB 4
#define NH 16
#define RR 512
#define CC 512
#define EMB 256
#define SD 16   // qkv dim per head
#define MH 16   // mlp hidden

typedef __attribute__((ext_vector_type(4))) float f32x4;
typedef __fp16 half2v __attribute__((ext_vector_type(2)));
typedef __fp16 half4v __attribute__((ext_vector_type(4)));
typedef __fp16 half8v __attribute__((ext_vector_type(8)));

union H8 { half8v v; half2v h[4]; __fp16 e[8]; };
union H4 { half4v v; half2v h[2]; __fp16 e[4]; };

// Guaranteed VOP3P packed f16 ops (R7-proven correct). Builtin fdot2 is used
// for dot contractions (R7-proven; raw-asm v_dot2 mis-encodes -> R8 failure).
__device__ __forceinline__ unsigned pk_fma(unsigned a, unsigned b, unsigned c) {
  unsigned d;
  asm("v_pk_fma_f16 %0, %1, %2, %3" : "=v"(d) : "v"(a), "v"(b), "v"(c));
  return d;
}
__device__ __forceinline__ unsigned pk_max(unsigned a, unsigned b) {
  unsigned d;
  asm("v_pk_max_f16 %0, %1, %2" : "=v"(d) : "v"(a), "v"(b));
  return d;
}
__device__ __forceinline__ half2v bch(unsigned u) { return __builtin_bit_cast(half2v, u); }
__device__ __forceinline__ unsigned bcu(half2v h) { return __builtin_bit_cast(unsigned, h); }

// ---------------------------------------------------------------------------
// Kernel 0: W[e][n] (256x256 fp32) -> WT[n][e] f16.  grid 192 x 256 thr.
// ---------------------------------------------------------------------------
__global__ __launch_bounds__(256) void prep_w(
    const float* __restrict__ Wq, const float* __restrict__ Wk,
    const float* __restrict__ Wv, __fp16* __restrict__ WT) {
  int bi = blockIdx.x;
  int mat = bi >> 6, chunk = bi & 63;
  const float* src = (mat == 0) ? Wq : (mat == 1) ? Wk : Wv;
  __fp16* dst = WT + mat * (EMB * EMB);
  int t = threadIdx.x;
  int n = chunk * 4 + (t >> 6);
  int e0 = (t & 63) * 4;
  H4 v;
#pragma unroll
  for (int j = 0; j < 4; ++j) v.e[j] = (__fp16)src[(e0 + j) * EMB + n];
  *(half4v*)(dst + n * EMB + e0) = v.v;
}

// ---------------------------------------------------------------------------
// Kernel 1: projections (f16 MFMA). Wave converts 16 X-rows to f16 once,
// reuses across 4 heads. 1536 waves -> 384 blocks x 256 thr.
//   mat 0: Q[b,h,r,s]; mat 1: K[b,h,c,s]; mat 2: VT[b,h,s,c].
// ---------------------------------------------------------------------------
__global__ __launch_bounds__(256) void proj_kernel(
    const float* __restrict__ rowe, const float* __restrict__ cole,
    const __fp16* __restrict__ WT,
    __fp16* __restrict__ Q, __fp16* __restrict__ K,
    __fp16* __restrict__ VT) {
  int tid = threadIdx.x;
  int wid = tid >> 6, lane = tid & 63, l15 = lane & 15, quad = lane >> 4;
  int wt = blockIdx.x * 4 + wid;        // 0..1535
  int mat = wt >> 9;                    // 0=Q 1=K 2=V
  int t = wt & 511;
  int rt = t >> 2, ng = t & 3;          // rt 0..127, head group 0..3
  const float* X = (mat == 0) ? rowe : cole;
  const __fp16* Wm = WT + mat * (EMB * EMB);
  const float* xrow = X + (size_t)(rt * 16 + l15) * EMB + quad * 8;

  half8v xf[8];
#pragma unroll
  for (int e = 0; e < 8; ++e) {
    f32x4 b0 = *(const f32x4*)(xrow + e * 32);
    f32x4 b1 = *(const f32x4*)(xrow + e * 32 + 4);
    H8 x;
    x.h[0] = __builtin_amdgcn_cvt_pkrtz(b0[0], b0[1]);
    x.h[1] = __builtin_amdgcn_cvt_pkrtz(b0[2], b0[3]);
    x.h[2] = __builtin_amdgcn_cvt_pkrtz(b1[0], b1[1]);
    x.h[3] = __builtin_amdgcn_cvt_pkrtz(b1[2], b1[3]);
    xf[e] = x.v;
  }
  int row = rt * 16 + l15;
  int b = row >> 9, loc = row & 511;
#pragma unroll
  for (int hh = 0; hh < 4; ++hh) {
    int nt = ng * 4 + hh;
    const half8v* ap = (const half8v*)(Wm + (nt * 16 + l15) * EMB + quad * 8);
    f32x4 acc = {0.f, 0.f, 0.f, 0.f};
#pragma unroll
    for (int e = 0; e < 8; ++e)
      acc = __builtin_amdgcn_mfma_f32_16x16x32_f16(ap[e * 4], xf[e], acc, 0, 0, 0);
    if (mat < 2) {
      H4 pk;
      pk.h[0] = __builtin_amdgcn_cvt_pkrtz(acc[0], acc[1]);
      pk.h[1] = __builtin_amdgcn_cvt_pkrtz(acc[2], acc[3]);
      __fp16* dst = ((mat == 0) ? Q : K) +
          ((size_t)((b * NH + nt) * 512 + loc) * SD + quad * 4);
      *(half4v*)dst = pk.v;
    } else {
#pragma unroll
      for (int i = 0; i < 4; ++i)
        VT[(size_t)((b * NH + nt) * SD + quad * 4 + i) * CC + loc] = (__fp16)acc[i];
    }
  }
}

// ---------------------------------------------------------------------------
// Kernel 2: fused mixed-score attention, single-phase, register-resident P.
// grid (32 rb, 16 h, 4 b) x 256 thr. Block = 1 row-tile (16 r) x 4 c-chunks.
// Key layout identity: the S^T QK-MFMA C-layout (r=lane&15, c=quad*4+i) is
// exactly the A-operand layout of v_mfma_f32_16x16x16_f16 (m=lane&15,
// k=quad*4+j). So P goes straight from the MLP registers into the P.V MFMA —
// no LDS score buffer, no phase 2, no swizzle.
// Per iter: MFMA S^T -> packed-f16 MLP -> exp2 (no-max softmax, R9-proven)
//           -> pack half4 -> lsum fdot2 -> mfma_16x16x16(P, VTfrag, o).
// cost is batch-preloaded (8 x f32x4) to expose ONE memory latency, not 8.
// Merge: plain sums across 4 waves via 3.3 KB LDS, one barrier.
// ---------------------------------------------------------------------------
__global__ __launch_bounds__(256, 4) void attn_kernel(
    const __fp16* __restrict__ Q, const __fp16* __restrict__ K,
    const __fp16* __restrict__ VT, const float* __restrict__ cost,
    const float* __restrict__ m1w, const float* __restrict__ m1b,
    const float* __restrict__ m2w, const float* __restrict__ m2b,
    float* __restrict__ out) {
  __shared__ float Osh[3][256];                        // waves 1..3 partial O
  __shared__ float Lsh[4][16];                         // [wave][row] partial l
  int tid = threadIdx.x;
  int wid = tid >> 6, lane = tid & 63, l15 = lane & 15, quad = lane >> 4;
  int rb = blockIdx.x, h = blockIdx.y, b = blockIdx.z;
  int bh = b * NH + h;
  int r0 = rb * 16;
  int cbase = wid * 128;

  // per-head MLP weights, m-pairs packed into half2 bit-patterns (RTE casts)
  unsigned wa2[8], wc2[8], wd2[8], we2[8];
#pragma unroll
  for (int mp = 0; mp < 8; ++mp) {
    wa2[mp] = bcu(half2v{(__fp16)(m1w[(h * 2 + 0) * MH + 2 * mp] * 0.25f),
                         (__fp16)(m1w[(h * 2 + 0) * MH + 2 * mp + 1] * 0.25f)});
    wc2[mp] = bcu(half2v{(__fp16)m1w[(h * 2 + 1) * MH + 2 * mp],
                         (__fp16)m1w[(h * 2 + 1) * MH + 2 * mp + 1]});
    wd2[mp] = bcu(half2v{(__fp16)m1b[h * MH + 2 * mp],
                         (__fp16)m1b[h * MH + 2 * mp + 1]});
    we2[mp] = bcu(half2v{(__fp16)m2w[h * MH + 2 * mp],
                         (__fp16)m2w[h * MH + 2 * mp + 1]});
  }
  float wb2 = m2b[h];
  const half2v one2 = {(__fp16)1.f, (__fp16)1.f};

  // loop-invariant Q fragment (B-operand): zero for k>=16 -> kills junk K k>=16
  half8v qf = {0, 0, 0, 0, 0, 0, 0, 0};
  const __fp16* Qb = Q + (size_t)bh * RR * SD;
  if (quad < 2) qf = *(const half8v*)(Qb + (r0 + l15) * SD + quad * 8);

  const __fp16* Kb = K + ((size_t)bh * CC + cbase) * SD;
  const float* crow = cost + ((size_t)b * RR + r0 + l15) * CC + cbase;
  // V fragment rows for the P.V MFMA: B[k=c][n=s] -> lane l15 = s
  const __fp16* vrow = VT + ((size_t)bh * SD + l15) * CC + cbase;

  // ---- batch-preload all cost (8 x 16B, one latency exposure) ----
  f32x4 cf[8];
#pragma unroll
  for (int it = 0; it < 8; ++it)
    cf[it] = *(const f32x4*)(crow + it * 16 + quad * 4);

  // ---- single-phase loop: scores + MLP + exp + P.V (K depth-2 prefetch) ----
  const float L2E = 1.44269504088896f;
  float lsum = 0.f;
  f32x4 o = {0.f, 0.f, 0.f, 0.f};
  half8v kf0 = *(const half8v*)(Kb + l15 * SD + quad * 8);        // junk k>=16 ok
  half8v kf1 = *(const half8v*)(Kb + (16 + l15) * SD + quad * 8);
#pragma unroll
  for (int it = 0; it < 8; ++it) {
    int itn = (it + 2) & 7;                    // wrap: redundant reload, harmless
    half8v kf_n = *(const half8v*)(Kb + (itn * 16 + l15) * SD + quad * 8);
    half4v vf = *(const half4v*)(vrow + it * 16 + quad * 4);

    f32x4 acc = {0.f, 0.f, 0.f, 0.f};
    acc = __builtin_amdgcn_mfma_f32_16x16x32_f16(kf0, qf, acc, 0, 0, 0);
    // lane: r = r0+l15 (fixed), local c = it*16 + 4*quad + i
    float pv[4];
#pragma unroll
    for (int i = 0; i < 4; ++i) {
      unsigned x2 = bcu(__builtin_amdgcn_cvt_pkrtz(acc[i], acc[i]));
      unsigned c2 = bcu(__builtin_amdgcn_cvt_pkrtz(cf[it][i], cf[it][i]));
      float s = wb2;
#pragma unroll
      for (int mp = 0; mp < 8; ++mp) {
        unsigned t1 = pk_fma(wc2[mp], c2, wd2[mp]);
        t1 = pk_fma(wa2[mp], x2, t1);
        t1 = pk_max(t1, 0u);
        s = __builtin_amdgcn_fdot2(bch(we2[mp]), bch(t1), s, false);
      }
      pv[i] = __builtin_amdgcn_exp2f(fmaf(s, L2E, -6.f));  // scaled exp, 2^-6
    }
    H4 pk;
    pk.h[0] = __builtin_amdgcn_cvt_pkrtz(pv[0], pv[1]);
    pk.h[1] = __builtin_amdgcn_cvt_pkrtz(pv[2], pv[3]);
    lsum = __builtin_amdgcn_fdot2(pk.h[0], one2, lsum, false);
    lsum = __builtin_amdgcn_fdot2(pk.h[1], one2, lsum, false);
    // P (A-layout m=r,k=c) x V^T fragment (B-layout k=c,n=s) -> O^T in C-layout
    o = __builtin_amdgcn_mfma_f32_16x16x16f16(pk.v, vf, o, 0, 0, 0);
    kf0 = kf1; kf1 = kf_n;
  }
  lsum += __shfl_xor(lsum, 16);
  lsum += __shfl_xor(lsum, 32);               // per-row (l15) partial l

  // ---- merge the four c-chunks: plain sums (no-max softmax), 1 barrier ----
  if (quad == 0) Lsh[wid][l15] = lsum;
  if (wid != 0) {
#pragma unroll
    for (int i = 0; i < 4; ++i) Osh[wid - 1][(quad * 4 + i) * 16 + l15] = o[i];
  }
  __syncthreads();
  if (wid == 0) {
#pragma unroll
    for (int i = 0; i < 4; ++i) {
      int r = quad * 4 + i;
      float l = Lsh[0][r] + Lsh[1][r] + Lsh[2][r] + Lsh[3][r];
      float num = o[i] + Osh[0][r * 16 + l15] + Osh[1][r * 16 + l15] +
                  Osh[2][r * 16 + l15];
      out[((size_t)b * RR + r0 + r) * (NH * SD) + h * SD + l15] = num / l;
    }
  }
}

// ---------------------------------------------------------------------------
extern "C" void kernel_launch(void* const* d_in, const int* in_sizes, int n_in,
                              void* d_out, int out_size, void* d_ws, size_t ws_size,
                              hipStream_t stream) {
  const float* rowe = (const float*)d_in[0];
  const float* cole = (const float*)d_in[1];
  const float* cost = (const float*)d_in[2];
  const float* Wq   = (const float*)d_in[3];
  const float* Wk   = (const float*)d_in[4];
  const float* Wv   = (const float*)d_in[5];
  const float* m1w  = (const float*)d_in[6];
  const float* m1b  = (const float*)d_in[7];
  const float* m2w  = (const float*)d_in[8];
  const float* m2b  = (const float*)d_in[9];
  float* outp = (float*)d_out;

  // workspace layout (f16 elements):
  //   Q  [4,16,512,16]  @ 0        (524288)
  //   K  [4,16,512,16]  @ 524288   (524288)
  //   VT [4,16,16,512]  @ 1048576  (524288)
  //   WT [3,256,256]    @ 1572864  (196608)   -> 3538944 bytes total
  __fp16* ws = (__fp16*)d_ws;
  __fp16* Qw  = ws;
  __fp16* Kw  = ws + 524288;
  __fp16* VTw = ws + 1048576;
  __fp16* WTw = ws + 1572864;

  prep_w<<<dim3(192, 1, 1), 256, 0, stream>>>(Wq, Wk, Wv, WTw);
  proj_kernel<<<dim3(384, 1, 1), 256, 0, stream>>>(rowe, cole, WTw, Qw, Kw, VTw);
  attn_kernel<<<dim3(32, NH, NB), 256, 0, stream>>>(Qw, Kw, VTw, cost,
                                                    m1w, m1b, m2w, m2b, outp);
}